// Round 15
// baseline (244.985 us; speedup 1.0000x reference)
//
#include <hip/hip_runtime.h>
#include <hip/hip_bf16.h>

#define NROWS 2048
#define CCH   64
#define FDIM  256
#define CF    16384   // C*F
#define NF    (NROWS * FDIM)
#define EPSV  1e-3f

typedef __attribute__((ext_vector_type(8))) short  short8;
typedef __attribute__((ext_vector_type(4))) float  f32x4;

__device__ __forceinline__ ushort f2bf(float f) {
  union { float f; unsigned u; } v; v.f = f;
  unsigned r = v.u + 0x7fffu + ((v.u >> 16) & 1u);
  return (ushort)(r >> 16);
}
__device__ __forceinline__ float bf_lo(unsigned u) {
  union { unsigned u; float f; } v; v.u = u << 16; return v.f;
}
__device__ __forceinline__ float bf_hi(unsigned u) {
  union { unsigned u; float f; } v; v.u = u & 0xffff0000u; return v.f;
}
__device__ __forceinline__ unsigned pk2(float a, float b) {
  __hip_bfloat162 h = __float22bfloat162_rn(float2{a, b});
  union { __hip_bfloat162 h; unsigned u; } cv; cv.h = h; return cv.u;
}
__device__ __forceinline__ void gll16(const void* g, void* l) {
  __builtin_amdgcn_global_load_lds(
      (const __attribute__((address_space(1))) unsigned*)g,
      (__attribute__((address_space(3))) unsigned*)l, 16, 0, 0);
}
// LDS-only barrier: orders ds ops without draining vmcnt (HK/T4 pattern) —
// keeps in-flight global loads alive across the epilogue.
__device__ __forceinline__ void lds_barrier() {
  asm volatile("s_waitcnt lgkmcnt(0)" ::: "memory");
  __builtin_amdgcn_s_barrier();
}

// ---------------- prep: BN0 stats + x->xt (c,n,f) bf16  ||  w cvt ----------------
// grid 1536: blocks 0..1023 stats_xt (c = b&63, nb = b>>6); blocks 1024.. cvt.
__global__ __launch_bounds__(256) void prep(const float* __restrict__ x,
                                            ushort* __restrict__ xt,
                                            float* __restrict__ ps,
                                            float* __restrict__ pq,
                                            const float* __restrict__ w0,
                                            const float* __restrict__ w1,
                                            ushort* __restrict__ o0,
                                            ushort* __restrict__ o1) {
  __shared__ float red[2][4][64][4];   // 8KB
  const int b = blockIdx.x;
  const int t = threadIdx.x;
  if (b < 1024) {
    const int c  = b & 63;
    const int nb = b >> 6;
    const int cg = t & 63;             // float4 col group
    const int rg = t >> 6;             // 0..3
    const float4* src = (const float4*)x;       // idx = row*4096 + c*64 + cg
    ushort4* dst = (ushort4*)xt;                // idx = c*131072 + row*64 + cg
    float s0 = 0, s1 = 0, s2 = 0, s3 = 0, q0 = 0, q1 = 0, q2 = 0, q3 = 0;
#pragma unroll 8
    for (int i = 0; i < 32; ++i) {
      const int row = nb * 128 + rg * 32 + i;
      float4 v = src[(size_t)row * 4096 + c * 64 + cg];
      s0 += v.x; q0 += v.x * v.x;
      s1 += v.y; q1 += v.y * v.y;
      s2 += v.z; q2 += v.z * v.z;
      s3 += v.w; q3 += v.w * v.w;
      ushort4 u;
      u.x = f2bf(v.x); u.y = f2bf(v.y); u.z = f2bf(v.z); u.w = f2bf(v.w);
      dst[(size_t)c * 131072 + row * 64 + cg] = u;
    }
    red[0][rg][cg][0] = s0; red[0][rg][cg][1] = s1;
    red[0][rg][cg][2] = s2; red[0][rg][cg][3] = s3;
    red[1][rg][cg][0] = q0; red[1][rg][cg][1] = q1;
    red[1][rg][cg][2] = q2; red[1][rg][cg][3] = q3;
    __syncthreads();
    if (t < 128) {
      const int which = t >> 6;        // 0=s, 1=q
      const int g = t & 63;
      float* dstp = which ? pq : ps;
#pragma unroll
      for (int j = 0; j < 4; ++j) {
        float v = red[which][0][g][j] + red[which][1][g][j] +
                  red[which][2][g][j] + red[which][3][g][j];
        dstp[(size_t)nb * CF + c * FDIM + g * 4 + j] = v;
      }
    }
  } else {
    const int n4 = CCH * FDIM * FDIM / 4;
    const size_t stride = (size_t)512 * 256;
    for (size_t i = (size_t)(b - 1024) * 256 + t; i < (size_t)(2 * n4); i += stride) {
      const float* src = (i < (size_t)n4) ? w0 : w1;
      ushort* dst = (i < (size_t)n4) ? o0 : o1;
      size_t j = (i < (size_t)n4) ? i : i - n4;
      float4 v = ((const float4*)src)[j];
      ushort4 u;
      u.x = f2bf(v.x); u.y = f2bf(v.y); u.z = f2bf(v.z); u.w = f2bf(v.w);
      ((ushort4*)dst)[j] = u;
    }
  }
}

// ---------------- fused GEMM: 4-tile persistent blocks, continuous demand ----------------
// Grid 1024 = 64c x 4bn x 4bg. Block: W [64 o][256 k] = 32KB staged once;
// FOUR BM=128 tiles (bm = bg*4 + ti). A in two alternating full reg buffers
// (64 VGPR each); tile ti+1's 16-load burst issues at tile-ti top (separate
// buffer -> no WAR; compiler emits counted vmcnt so loads span the tile).
// Per-tile epilogue via dedicated Cs (32KB) with RAW lgkmcnt-only barriers
// (vmcnt never drained mid-kernel after the one prologue drain).
// BN finalize FOLDED into prologue (block reduces its 256 cols from partials).
// MODE 0: A=relu(bn0(xt)); epi ybf (c,n,f) + BN1 partials (per-bg).
// MODE 1: A=relu(bn1(ybf)); epi out(n,cf) = xres + acc + bias.
template <int MODE, int NPARTS>
__global__ __launch_bounds__(256, 2) void gemm_fused(const ushort* __restrict__ Act,
                                                     const ushort* __restrict__ W,
                                                     const float* __restrict__ bias,
                                                     const float* __restrict__ ps,
                                                     const float* __restrict__ pq,
                                                     const float* __restrict__ gam,
                                                     const float* __restrict__ bet,
                                                     const float* __restrict__ xres,
                                                     ushort* __restrict__ Ybf,
                                                     float* __restrict__ outf,
                                                     float* __restrict__ ps1,
                                                     float* __restrict__ pq1) {
  __shared__ __align__(16) ushort Ws[2][64 * 128];    // 32KB persistent W
  __shared__ __align__(16) float Cs[128 * 64];        // 32KB epilogue staging
  __shared__ float scl[256], shf[256];                // 2KB
  __shared__ float sstat[2][4][4][16];                // 2KB (MODE0)

  const int t = threadIdx.x;
  const int lane = t & 63, wid = t >> 6;
  const int lm = lane & 15, lg = lane >> 4;

  // bijective XCD swizzle (nwg=1024): XCD j gets wg in [j*128,(j+1)*128) = 8 c's
  const int h  = blockIdx.x;
  const int wg = ((h & 7) << 7) | (h >> 3);
  const int c  = wg >> 4, bn = (wg >> 2) & 3, bg = wg & 3;

  // ---- W staging: both k-halves, 8 gll16/thread ----
  const int srow = t >> 4;            // 0..15
  const int sb   = (t & 15) * 16;     // byte-in-half-row
  const int gsb  = sb ^ ((srow & 7) << 4);
  const char* Wrow = (const char*)(W + ((size_t)c * FDIM + bn * 64) * FDIM);
  char* Ws0 = (char*)&Ws[0][0];
  char* Ws1 = (char*)&Ws[1][0];
#pragma unroll
  for (int i = 0; i < 4; ++i) {
    const int row = i * 16 + srow;   // 0..63
    gll16(Wrow + (size_t)row * 512 + gsb,       Ws0 + row * 256 + sb);
    gll16(Wrow + (size_t)row * 512 + 256 + gsb, Ws1 + row * 256 + sb);
  }

  // ---- A bases (tile 0); tile ti adds ti*128*FDIM ----
  const ushort* Ab[2];
#pragma unroll
  for (int m = 0; m < 2; ++m)
    Ab[m] = Act + (size_t)c * NF
               + (size_t)(bg * 512 + wid * 32 + m * 16 + lm) * FDIM + lg * 8;

  uint4 ra[8][2], rb[8][2];

#define LOADT(buf, ti)                                                      \
  _Pragma("unroll")                                                         \
  for (int ks = 0; ks < 8; ++ks)                                            \
    _Pragma("unroll")                                                       \
    for (int m = 0; m < 2; ++m)                                             \
      buf[ks][m] = *(const uint4*)(Ab[m] + (size_t)(ti) * 128 * FDIM + ks * 32); \
  __builtin_amdgcn_sched_barrier(0);

  LOADT(ra, 0)

  // ---- folded BN finalize: this block's 256 columns (col = c*FDIM + t) ----
  {
    float s = 0, q = 0;
#pragma unroll
    for (int j = 0; j < NPARTS; ++j) {
      s += ps[(size_t)j * CF + c * FDIM + t];
      q += pq[(size_t)j * CF + c * FDIM + t];
    }
    const float mean = s * (1.0f / NROWS);
    const float var  = q * (1.0f / NROWS) - mean * mean;
    const float sc   = gam[c * FDIM + t] * rsqrtf(var + EPSV);
    scl[t] = sc;
    shf[t] = bet[c * FDIM + t] - mean * sc;
  }

  float bregs[4];
#pragma unroll
  for (int n = 0; n < 4; ++n)
    bregs[n] = bias[c * FDIM + bn * 64 + n * 16 + lm];

  float tss[4] = {0.f, 0.f, 0.f, 0.f}, tqq[4] = {0.f, 0.f, 0.f, 0.f};
  f32x4 acc[2][4];

  __syncthreads();   // THE one full drain: W staged + scl/shf ready

  // conv one ks from buf + its 4 MFMAs (compile-time W half/offset)
#define CMF(buf, ksg)                                                       \
  {                                                                         \
    float4 sc0 = *(const float4*)&scl[(ksg) * 32 + lg * 8];                 \
    float4 sc1 = *(const float4*)&scl[(ksg) * 32 + lg * 8 + 4];             \
    float4 sh0 = *(const float4*)&shf[(ksg) * 32 + lg * 8];                 \
    float4 sh1 = *(const float4*)&shf[(ksg) * 32 + lg * 8 + 4];             \
    short8 af[2];                                                           \
    _Pragma("unroll")                                                       \
    for (int m = 0; m < 2; ++m) {                                           \
      uint4 u = buf[ksg][m];                                                \
      float v0 = bf_lo(u.x), v1 = bf_hi(u.x), v2 = bf_lo(u.y), v3 = bf_hi(u.y); \
      float v4 = bf_lo(u.z), v5 = bf_hi(u.z), v6 = bf_lo(u.w), v7 = bf_hi(u.w); \
      v0 = fmaxf(fmaf(v0, sc0.x, sh0.x), 0.f);                              \
      v1 = fmaxf(fmaf(v1, sc0.y, sh0.y), 0.f);                              \
      v2 = fmaxf(fmaf(v2, sc0.z, sh0.z), 0.f);                              \
      v3 = fmaxf(fmaf(v3, sc0.w, sh0.w), 0.f);                              \
      v4 = fmaxf(fmaf(v4, sc1.x, sh1.x), 0.f);                              \
      v5 = fmaxf(fmaf(v5, sc1.y, sh1.y), 0.f);                              \
      v6 = fmaxf(fmaf(v6, sc1.z, sh1.z), 0.f);                              \
      v7 = fmaxf(fmaf(v7, sc1.w, sh1.w), 0.f);                              \
      union { short8 s; unsigned u[4]; } pkd;                               \
      pkd.u[0] = pk2(v0, v1); pkd.u[1] = pk2(v2, v3);                       \
      pkd.u[2] = pk2(v4, v5); pkd.u[3] = pk2(v6, v7);                       \
      af[m] = pkd.s;                                                        \
    }                                                                       \
    const char* WsH = ((ksg) < 4) ? Ws0 : Ws1;                              \
    const int ksl = (ksg) & 3;                                              \
    short8 bv[4];                                                           \
    _Pragma("unroll")                                                       \
    for (int n = 0; n < 4; ++n) {                                           \
      const int ro = n * 16 + lm;                                           \
      const int byt = (ksl * 64 + lg * 16) ^ ((ro & 7) << 4);               \
      bv[n] = *(const short8*)(WsH + ro * 256 + byt);                       \
    }                                                                       \
    _Pragma("unroll")                                                       \
    for (int m = 0; m < 2; ++m)                                             \
      _Pragma("unroll")                                                     \
      for (int n = 0; n < 4; ++n)                                           \
        acc[m][n] = __builtin_amdgcn_mfma_f32_16x16x32_bf16(af[m], bv[n],   \
                                                            acc[m][n], 0, 0, 0); \
  }

#define TILE(ti, CUR, NXT, DOPRE)                                           \
  {                                                                         \
    if (DOPRE) { LOADT(NXT, (ti) + 1) }   /* next burst flies over tile */  \
    _Pragma("unroll")                                                       \
    for (int m = 0; m < 2; ++m)                                             \
      _Pragma("unroll")                                                     \
      for (int n = 0; n < 4; ++n) acc[m][n] = (f32x4){0.f, 0.f, 0.f, 0.f};  \
    CMF(CUR, 0) CMF(CUR, 1) CMF(CUR, 2) CMF(CUR, 3)                         \
    CMF(CUR, 4) CMF(CUR, 5) CMF(CUR, 6) CMF(CUR, 7)                         \
    if (MODE == 0) {                                                        \
      _Pragma("unroll")                                                     \
      for (int n = 0; n < 4; ++n)                                           \
        _Pragma("unroll")                                                   \
        for (int m = 0; m < 2; ++m)                                         \
          _Pragma("unroll")                                                 \
          for (int j = 0; j < 4; ++j) {                                     \
            const float v = acc[m][n][j] + bregs[n];                        \
            tss[n] += v; tqq[n] += v * v;                                   \
          }                                                                 \
    }                                                                       \
    /* epilogue: Cs write -> LDS-only barrier -> coalesced writeout */      \
    _Pragma("unroll")                                                       \
    for (int m = 0; m < 2; ++m) {                                           \
      const int rbase = wid * 32 + m * 16 + lg * 4;                         \
      const int xd = lg << 4;                                               \
      _Pragma("unroll")                                                     \
      for (int n = 0; n < 4; ++n) {                                         \
        const int col = n * 16 + lm;                                        \
        _Pragma("unroll")                                                   \
        for (int j = 0; j < 4; ++j)                                         \
          Cs[(rbase + j) * 64 + (col ^ xd)] = acc[m][n][j] + bregs[n];      \
      }                                                                     \
    }                                                                       \
    lds_barrier();                                                          \
    {                                                                       \
      const int bm = bg * 4 + (ti);                                         \
      const int rt = t >> 3;           /* 0..31 */                          \
      const int pcol = (t & 7) * 8;    /* 0..56 */                          \
      _Pragma("unroll")                                                     \
      for (int rb2 = 0; rb2 < 4; ++rb2) {                                   \
        const int row = rb2 * 32 + rt;                                      \
        const int xd2 = ((row >> 2) & 3) << 4;                              \
        f32x4 v0 = *(const f32x4*)&Cs[row * 64 + (pcol ^ xd2)];             \
        f32x4 v1 = *(const f32x4*)&Cs[row * 64 + ((pcol + 4) ^ xd2)];       \
        if (MODE == 0) {                                                    \
          const size_t gofs = (size_t)c * NF                                \
              + (size_t)(bm * 128 + row) * FDIM + bn * 64 + pcol;           \
          uint4 u;                                                          \
          u.x = pk2(v0[0], v0[1]); u.y = pk2(v0[2], v0[3]);                 \
          u.z = pk2(v1[0], v1[1]); u.w = pk2(v1[2], v1[3]);                 \
          *(uint4*)(Ybf + gofs) = u;                                        \
        } else {                                                            \
          const size_t gofs = (size_t)(bm * 128 + row) * CF                 \
              + c * FDIM + bn * 64 + pcol;                                  \
          float4 x0 = *(const float4*)(xres + gofs);                        \
          float4 x1 = *(const float4*)(xres + gofs + 4);                    \
          float4 o0, o1;                                                    \
          o0.x = x0.x + v0[0]; o0.y = x0.y + v0[1];                         \
          o0.z = x0.z + v0[2]; o0.w = x0.w + v0[3];                         \
          o1.x = x1.x + v1[0]; o1.y = x1.y + v1[1];                         \
          o1.z = x1.z + v1[2]; o1.w = x1.w + v1[3];                         \
          *(float4*)(outf + gofs) = o0;                                     \
          *(float4*)(outf + gofs + 4) = o1;                                 \
        }                                                                   \
      }                                                                     \
    }                                                                       \
    lds_barrier();   /* Cs reads done before next tile overwrites */        \
  }

  TILE(0, ra, rb, 1)
  TILE(1, rb, ra, 1)
  TILE(2, ra, rb, 1)
  TILE(3, rb, ra, 0)

  if (MODE == 0) {
    // ---- BN1 partial stats: one reduce per block (covers 4 tiles) ----
#pragma unroll
    for (int n = 0; n < 4; ++n) {
      float ss = tss[n], qq = tqq[n];
      ss += __shfl_xor(ss, 16); ss += __shfl_xor(ss, 32);
      qq += __shfl_xor(qq, 16); qq += __shfl_xor(qq, 32);
      if (lg == 0) {
        sstat[0][wid][n][lm] = ss;
        sstat[1][wid][n][lm] = qq;
      }
    }
    lds_barrier();
    if (t < 128) {
      const int stat = t >> 6;
      const int idx = t & 63;
      const int n = idx >> 4, lmm = idx & 15;
      float v = sstat[stat][0][n][lmm] + sstat[stat][1][n][lmm] +
                sstat[stat][2][n][lmm] + sstat[stat][3][n][lmm];
      float* dst = stat ? pq1 : ps1;
      dst[(size_t)bg * CF + c * FDIM + bn * 64 + n * 16 + lmm] = v;
    }
  }
}

// ---------------- launch ----------------
extern "C" void kernel_launch(void* const* d_in, const int* in_sizes, int n_in,
                              void* d_out, int out_size, void* d_ws, size_t ws_size,
                              hipStream_t stream) {
  const float* x   = (const float*)d_in[0];
  const float* w0  = (const float*)d_in[1];
  const float* b0  = (const float*)d_in[2];
  const float* w1  = (const float*)d_in[3];
  const float* b1  = (const float*)d_in[4];
  const float* g0  = (const float*)d_in[5];
  const float* be0 = (const float*)d_in[6];
  const float* g1  = (const float*)d_in[7];
  const float* be1 = (const float*)d_in[8];
  float* out = (float*)d_out;

  char* ws = (char*)d_ws;
  float* ps0  = (float*)ws;                           // 16*CF
  float* pq0  = ps0 + (size_t)16 * CF;                // 16*CF
  float* ps1  = pq0 + (size_t)16 * CF;                // 4*CF
  float* pq1  = ps1 + (size_t)4 * CF;                 // 4*CF
  ushort* w0bf = (ushort*)(pq1 + (size_t)4 * CF);
  ushort* w1bf = w0bf + (size_t)CCH * FDIM * FDIM;
  ushort* xt   = w1bf + (size_t)CCH * FDIM * FDIM;    // (c,n,f) bf16, 67MB
  ushort* ybf  = xt + (size_t)NROWS * CF;             // (c,n,f) bf16, 67MB

  // BN0 stats + x->xt  ||  w0/w1 cvt (one merged kernel)
  prep<<<1536, 256, 0, stream>>>(x, xt, ps0, pq0, w0, w1, w0bf, w1bf);

  // linear0: finalize(BN0) folded into prologue; out ybf (c,n,f) + BN1 partials
  gemm_fused<0, 16><<<1024, 256, 0, stream>>>(
      xt, w0bf, b0, ps0, pq0, g0, be0, nullptr, ybf, nullptr, ps1, pq1);

  // linear1: finalize(BN1) folded; out(n,cf) = x + acc + b1
  gemm_fused<1, 4><<<1024, 256, 0, stream>>>(
      ybf, w1bf, b1, ps1, pq1, g1, be1, x, nullptr, out, nullptr, nullptr);
}

// Round 16
// 191.448 us; speedup vs baseline: 1.2796x; 1.2796x over previous
//
#include <hip/hip_runtime.h>
#include <hip/hip_bf16.h>

#define NROWS 2048
#define CCH   64
#define FDIM  256
#define CF    16384   // C*F
#define NF    (NROWS * FDIM)
#define EPSV  1e-3f

typedef __attribute__((ext_vector_type(8))) short  short8;
typedef __attribute__((ext_vector_type(4))) float  f32x4;

__device__ __forceinline__ ushort f2bf(float f) {
  union { float f; unsigned u; } v; v.f = f;
  unsigned r = v.u + 0x7fffu + ((v.u >> 16) & 1u);
  return (ushort)(r >> 16);
}
__device__ __forceinline__ float bf_lo(unsigned u) {
  union { unsigned u; float f; } v; v.u = u << 16; return v.f;
}
__device__ __forceinline__ float bf_hi(unsigned u) {
  union { unsigned u; float f; } v; v.u = u & 0xffff0000u; return v.f;
}
__device__ __forceinline__ unsigned pk2(float a, float b) {
  __hip_bfloat162 h = __float22bfloat162_rn(float2{a, b});
  union { __hip_bfloat162 h; unsigned u; } cv; cv.h = h; return cv.u;
}
__device__ __forceinline__ void gll16(const void* g, void* l) {
  __builtin_amdgcn_global_load_lds(
      (const __attribute__((address_space(1))) unsigned*)g,
      (__attribute__((address_space(3))) unsigned*)l, 16, 0, 0);
}

// ---------------- prep: BN0 stats + x->xt (c,n,f) bf16  ||  w cvt ----------------
// grid 1536: blocks 0..1023 stats_xt (c = b&63, nb = b>>6); blocks 1024.. cvt.
__global__ __launch_bounds__(256) void prep(const float* __restrict__ x,
                                            ushort* __restrict__ xt,
                                            float* __restrict__ ps,
                                            float* __restrict__ pq,
                                            const float* __restrict__ w0,
                                            const float* __restrict__ w1,
                                            ushort* __restrict__ o0,
                                            ushort* __restrict__ o1) {
  __shared__ float red[2][4][64][4];   // 8KB
  const int b = blockIdx.x;
  const int t = threadIdx.x;
  if (b < 1024) {
    const int c  = b & 63;
    const int nb = b >> 6;
    const int cg = t & 63;             // float4 col group
    const int rg = t >> 6;             // 0..3
    const float4* src = (const float4*)x;       // idx = row*4096 + c*64 + cg
    ushort4* dst = (ushort4*)xt;                // idx = c*131072 + row*64 + cg
    float s0 = 0, s1 = 0, s2 = 0, s3 = 0, q0 = 0, q1 = 0, q2 = 0, q3 = 0;
#pragma unroll 8
    for (int i = 0; i < 32; ++i) {
      const int row = nb * 128 + rg * 32 + i;
      float4 v = src[(size_t)row * 4096 + c * 64 + cg];
      s0 += v.x; q0 += v.x * v.x;
      s1 += v.y; q1 += v.y * v.y;
      s2 += v.z; q2 += v.z * v.z;
      s3 += v.w; q3 += v.w * v.w;
      ushort4 u;
      u.x = f2bf(v.x); u.y = f2bf(v.y); u.z = f2bf(v.z); u.w = f2bf(v.w);
      dst[(size_t)c * 131072 + row * 64 + cg] = u;
    }
    red[0][rg][cg][0] = s0; red[0][rg][cg][1] = s1;
    red[0][rg][cg][2] = s2; red[0][rg][cg][3] = s3;
    red[1][rg][cg][0] = q0; red[1][rg][cg][1] = q1;
    red[1][rg][cg][2] = q2; red[1][rg][cg][3] = q3;
    __syncthreads();
    if (t < 128) {
      const int which = t >> 6;        // 0=s, 1=q
      const int g = t & 63;
      float* dstp = which ? pq : ps;
#pragma unroll
      for (int j = 0; j < 4; ++j) {
        float v = red[which][0][g][j] + red[which][1][g][j] +
                  red[which][2][g][j] + red[which][3][g][j];
        dstp[(size_t)nb * CF + c * FDIM + g * 4 + j] = v;
      }
    }
  } else {
    const int n4 = CCH * FDIM * FDIM / 4;
    const size_t stride = (size_t)512 * 256;
    for (size_t i = (size_t)(b - 1024) * 256 + t; i < (size_t)(2 * n4); i += stride) {
      const float* src = (i < (size_t)n4) ? w0 : w1;
      ushort* dst = (i < (size_t)n4) ? o0 : o1;
      size_t j = (i < (size_t)n4) ? i : i - n4;
      float4 v = ((const float4*)src)[j];
      ushort4 u;
      u.x = f2bf(v.x); u.y = f2bf(v.y); u.z = f2bf(v.z); u.w = f2bf(v.w);
      ((ushort4*)dst)[j] = u;
    }
  }
}

// ---------------- fused batched channel GEMM: one-drain schedule (R13) ----------------
// Tile: BM=128 x BN=128 x K=256. Grid 2048 = 16bm x 2bn x 64c. 4 waves, each
// 32 rows x 128 cols (m=2, n=8 frags). ALL loads issue at t=0: 16 W gll16
// (both k-halves, XOR-swizzled src) + 16 A uint4 (full wave A-tile, 64 VGPR).
// BN finalize FOLDED into prologue (reduce NPARTS partials for this block's
// 256 cols; 2MB partials are L2-resident). One vmcnt(0)+barrier, then 128
// MFMAs barrier-free. MODE 0: A=relu(bn0(xt)); epi ybf (c,n,f) + BN1 partials.
// MODE 1: A=relu(bn1(ybf)); epi out(n,cf) = bf16x(xt) + acc + bias.
template <int MODE, int NPARTS>
__global__ __launch_bounds__(256, 2) void gemm_fused(const ushort* __restrict__ Act,
                                                     const ushort* __restrict__ W,
                                                     const float* __restrict__ bias,
                                                     const float* __restrict__ ps,
                                                     const float* __restrict__ pq,
                                                     const float* __restrict__ gam,
                                                     const float* __restrict__ bet,
                                                     const ushort* __restrict__ xtres,
                                                     ushort* __restrict__ Ybf,
                                                     float* __restrict__ outf,
                                                     float* __restrict__ ps1,
                                                     float* __restrict__ pq1) {
  __shared__ __align__(16) ushort Ws[2][128 * 128];   // 64KB; reused as Cs f32[128][128]
  __shared__ float scl[256], shf[256];                // 2KB
  __shared__ float sstat[2][4][8][16];                // 4KB (MODE0)

  const int t = threadIdx.x;
  const int lane = t & 63, wid = t >> 6;
  const int lm = lane & 15, lg = lane >> 4;

  // bijective XCD swizzle (nwg=2048): XCD j gets wg in [j*256,(j+1)*256)
  const int h  = blockIdx.x;
  const int wg = ((h & 7) << 8) | (h >> 3);
  const int bm = wg & 15, bn = (wg >> 4) & 1, c = wg >> 5;

  // ---- issue ALL W staging now (both halves, 16 gll16/thread) ----
  const int srow = t >> 4;            // 0..15
  const int sb   = (t & 15) * 16;     // 0..240 byte-in-half-row
  const int gsb  = sb ^ ((srow & 7) << 4);
  const char* Wrow = (const char*)(W + ((size_t)c * FDIM + bn * 128) * FDIM);
  char* Ws0 = (char*)&Ws[0][0];
  char* Ws1 = (char*)&Ws[1][0];
#pragma unroll
  for (int i = 0; i < 8; ++i) {
    const int row = i * 16 + srow;
    gll16(Wrow + (size_t)row * 512 + gsb,       Ws0 + row * 256 + sb);
    gll16(Wrow + (size_t)row * 512 + 256 + gsb, Ws1 + row * 256 + sb);
  }

  // ---- issue ALL A loads now: full wave-tile, 16 uint4/lane (64 VGPR) ----
  const ushort* AbU[2];
#pragma unroll
  for (int m = 0; m < 2; ++m)
    AbU[m] = Act + (size_t)c * NF
                 + (size_t)(bm * 128 + wid * 32 + m * 16 + lm) * FDIM + lg * 8;

  uint4 lu[8][2];
#pragma unroll
  for (int ks = 0; ks < 8; ++ks)
#pragma unroll
    for (int m = 0; m < 2; ++m)
      lu[ks][m] = *(const uint4*)(AbU[m] + ks * 32);
  __builtin_amdgcn_sched_barrier(0);

  // ---- folded BN finalize: this block's 256 columns (col = c*FDIM + t) ----
  {
    float s = 0, q = 0;
#pragma unroll
    for (int j = 0; j < NPARTS; ++j) {
      s += ps[(size_t)j * CF + c * FDIM + t];
      q += pq[(size_t)j * CF + c * FDIM + t];
    }
    const float mean = s * (1.0f / NROWS);
    const float var  = q * (1.0f / NROWS) - mean * mean;
    const float sc   = gam[c * FDIM + t] * rsqrtf(var + EPSV);
    scl[t] = sc;
    shf[t] = bet[c * FDIM + t] - mean * sc;
  }

  float bregs[8];
#pragma unroll
  for (int n = 0; n < 8; ++n)
    bregs[n] = bias[c * FDIM + bn * 128 + n * 16 + lm];

  f32x4 acc[2][8];
#pragma unroll
  for (int m = 0; m < 2; ++m)
#pragma unroll
    for (int n = 0; n < 8; ++n) acc[m][n] = (f32x4){0.f, 0.f, 0.f, 0.f};

  __syncthreads();   // THE one drain: W (both halves) + A + scl/shf all ready

  short8 af[4][2];   // converted fragments for current half

#define CONVH(kb)                                                           \
  _Pragma("unroll")                                                         \
  for (int ks = 0; ks < 4; ++ks) {                                          \
    float4 sc0 = *(const float4*)&scl[((kb) + ks) * 32 + lg * 8];           \
    float4 sc1 = *(const float4*)&scl[((kb) + ks) * 32 + lg * 8 + 4];       \
    float4 sh0 = *(const float4*)&shf[((kb) + ks) * 32 + lg * 8];           \
    float4 sh1 = *(const float4*)&shf[((kb) + ks) * 32 + lg * 8 + 4];       \
    _Pragma("unroll")                                                       \
    for (int m = 0; m < 2; ++m) {                                           \
      uint4 u = lu[(kb) + ks][m];                                           \
      float v0 = bf_lo(u.x), v1 = bf_hi(u.x), v2 = bf_lo(u.y), v3 = bf_hi(u.y); \
      float v4 = bf_lo(u.z), v5 = bf_hi(u.z), v6 = bf_lo(u.w), v7 = bf_hi(u.w); \
      v0 = fmaxf(fmaf(v0, sc0.x, sh0.x), 0.f);                              \
      v1 = fmaxf(fmaf(v1, sc0.y, sh0.y), 0.f);                              \
      v2 = fmaxf(fmaf(v2, sc0.z, sh0.z), 0.f);                              \
      v3 = fmaxf(fmaf(v3, sc0.w, sh0.w), 0.f);                              \
      v4 = fmaxf(fmaf(v4, sc1.x, sh1.x), 0.f);                              \
      v5 = fmaxf(fmaf(v5, sc1.y, sh1.y), 0.f);                              \
      v6 = fmaxf(fmaf(v6, sc1.z, sh1.z), 0.f);                              \
      v7 = fmaxf(fmaf(v7, sc1.w, sh1.w), 0.f);                              \
      union { short8 s; unsigned u[4]; } pkd;                               \
      pkd.u[0] = pk2(v0, v1); pkd.u[1] = pk2(v2, v3);                       \
      pkd.u[2] = pk2(v4, v5); pkd.u[3] = pk2(v6, v7);                       \
      af[ks][m] = pkd.s;                                                    \
    }                                                                       \
  }

#define MFMAH(WsH)                                                          \
  _Pragma("unroll")                                                         \
  for (int ksl = 0; ksl < 4; ++ksl) {                                       \
    short8 bv[8];                                                           \
    _Pragma("unroll")                                                       \
    for (int n = 0; n < 8; ++n) {                                           \
      const int ro = n * 16 + lm;                                           \
      const int byt = (ksl * 64 + lg * 16) ^ ((ro & 7) << 4);               \
      bv[n] = *(const short8*)((WsH) + ro * 256 + byt);                     \
    }                                                                       \
    _Pragma("unroll")                                                       \
    for (int m = 0; m < 2; ++m)                                             \
      _Pragma("unroll")                                                     \
      for (int n = 0; n < 8; ++n)                                           \
        acc[m][n] = __builtin_amdgcn_mfma_f32_16x16x32_bf16(af[ksl][m],     \
                        bv[n], acc[m][n], 0, 0, 0);                         \
  }

  CONVH(0)
  MFMAH(Ws0)
  CONVH(4)
  MFMAH(Ws1)

  if (MODE == 0) {
    // ---- BN1 column partial stats from f32 acc ----
#pragma unroll
    for (int n = 0; n < 8; ++n) {
      float ss = 0, qq = 0;
#pragma unroll
      for (int m = 0; m < 2; ++m)
#pragma unroll
        for (int j = 0; j < 4; ++j) {
          float v = acc[m][n][j] + bregs[n];
          ss += v; qq += v * v;
        }
      ss += __shfl_xor(ss, 16); ss += __shfl_xor(ss, 32);
      qq += __shfl_xor(qq, 16); qq += __shfl_xor(qq, 32);
      if (lg == 0) {
        sstat[0][wid][n][lm] = ss;
        sstat[1][wid][n][lm] = qq;
      }
    }
  }
  __syncthreads();   // all Ws reads done + sstat written; Ws reusable as Cs

  // ---- C -> LDS f32 [128][128], swz col^(((row>>2)&3)<<4) -> 2-way max ----
  float* Cs = (float*)&Ws[0][0];   // 64KB
#pragma unroll
  for (int m = 0; m < 2; ++m) {
    const int rbase = wid * 32 + m * 16 + lg * 4;
    const int xd = lg << 4;        // == ((rbase>>2)&3)<<4
#pragma unroll
    for (int n = 0; n < 8; ++n) {
      const int col = n * 16 + lm;
#pragma unroll
      for (int j = 0; j < 4; ++j)
        Cs[(rbase + j) * 128 + (col ^ xd)] = acc[m][n][j] + bregs[n];
    }
  }
  __syncthreads();

  // ---- coalesced writeout: 16 thr/row, 16 rows/pass, 8 passes ----
  const int prow = t >> 4;          // 0..15
  const int pcol = (t & 15) * 8;    // 0..120
#pragma unroll
  for (int rb = 0; rb < 8; ++rb) {
    const int row = rb * 16 + prow;
    const int xd = ((row >> 2) & 3) << 4;
    f32x4 v0 = *(const f32x4*)&Cs[row * 128 + (pcol ^ xd)];
    f32x4 v1 = *(const f32x4*)&Cs[row * 128 + ((pcol + 4) ^ xd)];
    if (MODE == 0) {
      const size_t gofs = (size_t)c * NF
                        + (size_t)(bm * 128 + row) * FDIM + bn * 128 + pcol;
      uint4 u;
      u.x = pk2(v0[0], v0[1]); u.y = pk2(v0[2], v0[3]);
      u.z = pk2(v1[0], v1[1]); u.w = pk2(v1[2], v1[3]);
      *(uint4*)(Ybf + gofs) = u;
    } else {
      // residual from xt (bf16 copy of x, (c,n,f) layout): halves FETCH
      const size_t gx = (size_t)c * NF
                      + (size_t)(bm * 128 + row) * FDIM + bn * 128 + pcol;
      uint4 xr = *(const uint4*)(xtres + gx);
      const size_t gofs = (size_t)(bm * 128 + row) * CF + c * FDIM + bn * 128 + pcol;
      float4 o0, o1;
      o0.x = bf_lo(xr.x) + v0[0]; o0.y = bf_hi(xr.x) + v0[1];
      o0.z = bf_lo(xr.y) + v0[2]; o0.w = bf_hi(xr.y) + v0[3];
      o1.x = bf_lo(xr.z) + v1[0]; o1.y = bf_hi(xr.z) + v1[1];
      o1.z = bf_lo(xr.w) + v1[2]; o1.w = bf_hi(xr.w) + v1[3];
      *(float4*)(outf + gofs) = o0;
      *(float4*)(outf + gofs + 4) = o1;
    }
  }

  if (MODE == 0) {
    // ---- partial stats writeout: 256 thr = 2 stats x 128 cols ----
    const int stat = t >> 7;
    const int idx = t & 127;
    const int n = idx >> 4, lmm = idx & 15;
    float v = sstat[stat][0][n][lmm] + sstat[stat][1][n][lmm] +
              sstat[stat][2][n][lmm] + sstat[stat][3][n][lmm];
    float* dst = stat ? pq1 : ps1;
    dst[(size_t)bm * CF + c * FDIM + bn * 128 + n * 16 + lmm] = v;
  }
}

// ---------------- launch ----------------
extern "C" void kernel_launch(void* const* d_in, const int* in_sizes, int n_in,
                              void* d_out, int out_size, void* d_ws, size_t ws_size,
                              hipStream_t stream) {
  const float* x   = (const float*)d_in[0];
  const float* w0  = (const float*)d_in[1];
  const float* b0  = (const float*)d_in[2];
  const float* w1  = (const float*)d_in[3];
  const float* b1  = (const float*)d_in[4];
  const float* g0  = (const float*)d_in[5];
  const float* be0 = (const float*)d_in[6];
  const float* g1  = (const float*)d_in[7];
  const float* be1 = (const float*)d_in[8];
  float* out = (float*)d_out;

  char* ws = (char*)d_ws;
  float* ps0  = (float*)ws;                           // 16*CF
  float* pq0  = ps0 + (size_t)16 * CF;                // 16*CF
  float* ps1  = pq0 + (size_t)16 * CF;                // 16*CF
  float* pq1  = ps1 + (size_t)16 * CF;                // 16*CF
  ushort* w0bf = (ushort*)(pq1 + (size_t)16 * CF);
  ushort* w1bf = w0bf + (size_t)CCH * FDIM * FDIM;
  ushort* xt   = w1bf + (size_t)CCH * FDIM * FDIM;    // (c,n,f) bf16, 67MB
  ushort* ybf  = xt + (size_t)NROWS * CF;             // (c,n,f) bf16, 67MB

  // BN0 stats + x->xt  ||  w0/w1 cvt (one merged kernel)
  prep<<<1536, 256, 0, stream>>>(x, xt, ps0, pq0, w0, w1, w0bf, w1bf);

  // linear0: BN0 finalize folded; A=relu(bn0(xt)); out ybf (c,n,f) + BN1 partials
  gemm_fused<0, 16><<<2048, 256, 0, stream>>>(
      xt, w0bf, b0, ps0, pq0, g0, be0, nullptr, ybf, nullptr, ps1, pq1);

  // linear1: BN1 finalize folded; A=relu(bn1(ybf)); out = bf16x(xt) + acc + b1
  gemm_fused<1, 16><<<2048, 256, 0, stream>>>(
      ybf, w1bf, b1, ps1, pq1, g1, be1, xt, nullptr, out, nullptr, nullptr);
}

// Round 17
// 178.569 us; speedup vs baseline: 1.3719x; 1.0721x over previous
//
#include <hip/hip_runtime.h>
#include <hip/hip_bf16.h>

#define NROWS 2048
#define CCH   64
#define FDIM  256
#define CF    16384   // C*F
#define NF    (NROWS * FDIM)
#define EPSV  1e-3f

typedef __attribute__((ext_vector_type(8))) short  short8;
typedef __attribute__((ext_vector_type(4))) float  f32x4;

__device__ __forceinline__ ushort f2bf(float f) {
  union { float f; unsigned u; } v; v.f = f;
  unsigned r = v.u + 0x7fffu + ((v.u >> 16) & 1u);
  return (ushort)(r >> 16);
}
__device__ __forceinline__ float bf_lo(unsigned u) {
  union { unsigned u; float f; } v; v.u = u << 16; return v.f;
}
__device__ __forceinline__ float bf_hi(unsigned u) {
  union { unsigned u; float f; } v; v.u = u & 0xffff0000u; return v.f;
}
__device__ __forceinline__ unsigned pk2(float a, float b) {
  __hip_bfloat162 h = __float22bfloat162_rn(float2{a, b});
  union { __hip_bfloat162 h; unsigned u; } cv; cv.h = h; return cv.u;
}
__device__ __forceinline__ void gll16(const void* g, void* l) {
  __builtin_amdgcn_global_load_lds(
      (const __attribute__((address_space(1))) unsigned*)g,
      (__attribute__((address_space(3))) unsigned*)l, 16, 0, 0);
}

// ---------------- prep: BN0 stats + x->xt (c,n,f) bf16  ||  w0 cvt ----------------
// grid 1280: blocks 0..1023 stats_xt (c = b&63, nb = b>>6); blocks 1024..1279 w0 cvt.
__global__ __launch_bounds__(256) void prep(const float* __restrict__ x,
                                            ushort* __restrict__ xt,
                                            float* __restrict__ ps,
                                            float* __restrict__ pq,
                                            const float* __restrict__ w0,
                                            ushort* __restrict__ o0) {
  __shared__ float red[2][4][64][4];   // 8KB
  const int b = blockIdx.x;
  const int t = threadIdx.x;
  if (b < 1024) {
    const int c  = b & 63;
    const int nb = b >> 6;
    const int cg = t & 63;             // float4 col group
    const int rg = t >> 6;             // 0..3
    const float4* src = (const float4*)x;       // idx = row*4096 + c*64 + cg
    ushort4* dst = (ushort4*)xt;                // idx = c*131072 + row*64 + cg
    float s0 = 0, s1 = 0, s2 = 0, s3 = 0, q0 = 0, q1 = 0, q2 = 0, q3 = 0;
#pragma unroll 8
    for (int i = 0; i < 32; ++i) {
      const int row = nb * 128 + rg * 32 + i;
      float4 v = src[(size_t)row * 4096 + c * 64 + cg];
      s0 += v.x; q0 += v.x * v.x;
      s1 += v.y; q1 += v.y * v.y;
      s2 += v.z; q2 += v.z * v.z;
      s3 += v.w; q3 += v.w * v.w;
      ushort4 u;
      u.x = f2bf(v.x); u.y = f2bf(v.y); u.z = f2bf(v.z); u.w = f2bf(v.w);
      dst[(size_t)c * 131072 + row * 64 + cg] = u;
    }
    red[0][rg][cg][0] = s0; red[0][rg][cg][1] = s1;
    red[0][rg][cg][2] = s2; red[0][rg][cg][3] = s3;
    red[1][rg][cg][0] = q0; red[1][rg][cg][1] = q1;
    red[1][rg][cg][2] = q2; red[1][rg][cg][3] = q3;
    __syncthreads();
    if (t < 128) {
      const int which = t >> 6;        // 0=s, 1=q
      const int g = t & 63;
      float* dstp = which ? pq : ps;
#pragma unroll
      for (int j = 0; j < 4; ++j) {
        float v = red[which][0][g][j] + red[which][1][g][j] +
                  red[which][2][g][j] + red[which][3][g][j];
        dstp[(size_t)nb * CF + c * FDIM + g * 4 + j] = v;
      }
    }
  } else {
    const int n4 = CCH * FDIM * FDIM / 4;
    const size_t stride = (size_t)256 * 256;
    for (size_t i = (size_t)(b - 1024) * 256 + t; i < (size_t)n4; i += stride) {
      float4 v = ((const float4*)w0)[i];
      ushort4 u;
      u.x = f2bf(v.x); u.y = f2bf(v.y); u.z = f2bf(v.z); u.w = f2bf(v.w);
      ((ushort4*)o0)[i] = u;
    }
  }
}

// ---------------- fused batched channel GEMM: one-drain schedule ----------------
// Tile: BM=128 x BN=128 x K=256. GEMM blocks 0..2047 = 16bm x 2bn x 64c. 4 waves,
// each 32 rows x 128 cols (m=2, n=8 frags). ALL loads issue at t=0: 16 W gll16
// (both k-halves, XOR-swizzled src) + 16 A uint4 (full wave A-tile, 64 VGPR).
// BN finalize FOLDED into prologue. One vmcnt(0)+barrier, then 128 MFMAs.
// MODE 0 extra: blocks 2048..2303 convert w1 f32->bf16 (rides gemm0's idle BW;
// stream order guarantees completion before gemm1).
// MODE 0: A=relu(bn0(xt)); epi ybf (c,n,f) + BN1 partials.
// MODE 1: A=relu(bn1(ybf)); epi out(n,cf) = bf16x(xt) + acc + bias.
template <int MODE, int NPARTS>
__global__ __launch_bounds__(256, 2) void gemm_fused(const ushort* __restrict__ Act,
                                                     const ushort* __restrict__ W,
                                                     const float* __restrict__ bias,
                                                     const float* __restrict__ ps,
                                                     const float* __restrict__ pq,
                                                     const float* __restrict__ gam,
                                                     const float* __restrict__ bet,
                                                     const ushort* __restrict__ xtres,
                                                     ushort* __restrict__ Ybf,
                                                     float* __restrict__ outf,
                                                     float* __restrict__ ps1,
                                                     float* __restrict__ pq1,
                                                     const float* __restrict__ wsrc,
                                                     ushort* __restrict__ wdst) {
  __shared__ __align__(16) ushort Ws[2][128 * 128];   // 64KB; reused as Cs f32[128][128]
  __shared__ float scl[256], shf[256];                // 2KB
  __shared__ float sstat[2][4][8][16];                // 4KB (MODE0)

  const int t = threadIdx.x;

  // ---- piggyback blocks (MODE 0 only): convert w1 in gemm0's BW shadow ----
  if (MODE == 0 && blockIdx.x >= 2048) {
    const int n4 = CCH * FDIM * FDIM / 4;
    const size_t stride = (size_t)256 * 256;
    for (size_t i = (size_t)(blockIdx.x - 2048) * 256 + t; i < (size_t)n4; i += stride) {
      float4 v = ((const float4*)wsrc)[i];
      ushort4 u;
      u.x = f2bf(v.x); u.y = f2bf(v.y); u.z = f2bf(v.z); u.w = f2bf(v.w);
      ((ushort4*)wdst)[i] = u;
    }
    return;
  }

  const int lane = t & 63, wid = t >> 6;
  const int lm = lane & 15, lg = lane >> 4;

  // bijective XCD swizzle (gemm blocks 0..2047): XCD j gets wg in [j*256,(j+1)*256)
  const int h  = blockIdx.x;
  const int wg = ((h & 7) << 8) | (h >> 3);
  const int bm = wg & 15, bn = (wg >> 4) & 1, c = wg >> 5;

  // ---- issue ALL W staging now (both halves, 16 gll16/thread) ----
  const int srow = t >> 4;            // 0..15
  const int sb   = (t & 15) * 16;     // 0..240 byte-in-half-row
  const int gsb  = sb ^ ((srow & 7) << 4);
  const char* Wrow = (const char*)(W + ((size_t)c * FDIM + bn * 128) * FDIM);
  char* Ws0 = (char*)&Ws[0][0];
  char* Ws1 = (char*)&Ws[1][0];
#pragma unroll
  for (int i = 0; i < 8; ++i) {
    const int row = i * 16 + srow;
    gll16(Wrow + (size_t)row * 512 + gsb,       Ws0 + row * 256 + sb);
    gll16(Wrow + (size_t)row * 512 + 256 + gsb, Ws1 + row * 256 + sb);
  }

  // ---- issue ALL A loads now: full wave-tile, 16 uint4/lane (64 VGPR) ----
  const ushort* AbU[2];
#pragma unroll
  for (int m = 0; m < 2; ++m)
    AbU[m] = Act + (size_t)c * NF
                 + (size_t)(bm * 128 + wid * 32 + m * 16 + lm) * FDIM + lg * 8;

  uint4 lu[8][2];
#pragma unroll
  for (int ks = 0; ks < 8; ++ks)
#pragma unroll
    for (int m = 0; m < 2; ++m)
      lu[ks][m] = *(const uint4*)(AbU[m] + ks * 32);
  __builtin_amdgcn_sched_barrier(0);

  // ---- folded BN finalize: this block's 256 columns (col = c*FDIM + t) ----
  {
    float s = 0, q = 0;
#pragma unroll
    for (int j = 0; j < NPARTS; ++j) {
      s += ps[(size_t)j * CF + c * FDIM + t];
      q += pq[(size_t)j * CF + c * FDIM + t];
    }
    const float mean = s * (1.0f / NROWS);
    const float var  = q * (1.0f / NROWS) - mean * mean;
    const float sc   = gam[c * FDIM + t] * rsqrtf(var + EPSV);
    scl[t] = sc;
    shf[t] = bet[c * FDIM + t] - mean * sc;
  }

  float bregs[8];
#pragma unroll
  for (int n = 0; n < 8; ++n)
    bregs[n] = bias[c * FDIM + bn * 128 + n * 16 + lm];

  f32x4 acc[2][8];
#pragma unroll
  for (int m = 0; m < 2; ++m)
#pragma unroll
    for (int n = 0; n < 8; ++n) acc[m][n] = (f32x4){0.f, 0.f, 0.f, 0.f};

  __syncthreads();   // THE one drain: W (both halves) + A + scl/shf all ready

  short8 af[4][2];   // converted fragments for current half

#define CONVH(kb)                                                           \
  _Pragma("unroll")                                                         \
  for (int ks = 0; ks < 4; ++ks) {                                          \
    float4 sc0 = *(const float4*)&scl[((kb) + ks) * 32 + lg * 8];           \
    float4 sc1 = *(const float4*)&scl[((kb) + ks) * 32 + lg * 8 + 4];       \
    float4 sh0 = *(const float4*)&shf[((kb) + ks) * 32 + lg * 8];           \
    float4 sh1 = *(const float4*)&shf[((kb) + ks) * 32 + lg * 8 + 4];       \
    _Pragma("unroll")                                                       \
    for (int m = 0; m < 2; ++m) {                                           \
      uint4 u = lu[(kb) + ks][m];                                           \
      float v0 = bf_lo(u.x), v1 = bf_hi(u.x), v2 = bf_lo(u.y), v3 = bf_hi(u.y); \
      float v4 = bf_lo(u.z), v5 = bf_hi(u.z), v6 = bf_lo(u.w), v7 = bf_hi(u.w); \
      v0 = fmaxf(fmaf(v0, sc0.x, sh0.x), 0.f);                              \
      v1 = fmaxf(fmaf(v1, sc0.y, sh0.y), 0.f);                              \
      v2 = fmaxf(fmaf(v2, sc0.z, sh0.z), 0.f);                              \
      v3 = fmaxf(fmaf(v3, sc0.w, sh0.w), 0.f);                              \
      v4 = fmaxf(fmaf(v4, sc1.x, sh1.x), 0.f);                              \
      v5 = fmaxf(fmaf(v5, sc1.y, sh1.y), 0.f);                              \
      v6 = fmaxf(fmaf(v6, sc1.z, sh1.z), 0.f);                              \
      v7 = fmaxf(fmaf(v7, sc1.w, sh1.w), 0.f);                              \
      union { short8 s; unsigned u[4]; } pkd;                               \
      pkd.u[0] = pk2(v0, v1); pkd.u[1] = pk2(v2, v3);                       \
      pkd.u[2] = pk2(v4, v5); pkd.u[3] = pk2(v6, v7);                       \
      af[ks][m] = pkd.s;                                                    \
    }                                                                       \
  }

#define MFMAH(WsH)                                                          \
  _Pragma("unroll")                                                         \
  for (int ksl = 0; ksl < 4; ++ksl) {                                       \
    short8 bv[8];                                                           \
    _Pragma("unroll")                                                       \
    for (int n = 0; n < 8; ++n) {                                           \
      const int ro = n * 16 + lm;                                           \
      const int byt = (ksl * 64 + lg * 16) ^ ((ro & 7) << 4);               \
      bv[n] = *(const short8*)((WsH) + ro * 256 + byt);                     \
    }                                                                       \
    _Pragma("unroll")                                                       \
    for (int m = 0; m < 2; ++m)                                             \
      _Pragma("unroll")                                                     \
      for (int n = 0; n < 8; ++n)                                           \
        acc[m][n] = __builtin_amdgcn_mfma_f32_16x16x32_bf16(af[ksl][m],     \
                        bv[n], acc[m][n], 0, 0, 0);                         \
  }

  CONVH(0)
  MFMAH(Ws0)
  CONVH(4)
  MFMAH(Ws1)

  if (MODE == 0) {
    // ---- BN1 column partial stats from f32 acc ----
#pragma unroll
    for (int n = 0; n < 8; ++n) {
      float ss = 0, qq = 0;
#pragma unroll
      for (int m = 0; m < 2; ++m)
#pragma unroll
        for (int j = 0; j < 4; ++j) {
          float v = acc[m][n][j] + bregs[n];
          ss += v; qq += v * v;
        }
      ss += __shfl_xor(ss, 16); ss += __shfl_xor(ss, 32);
      qq += __shfl_xor(qq, 16); qq += __shfl_xor(qq, 32);
      if (lg == 0) {
        sstat[0][wid][n][lm] = ss;
        sstat[1][wid][n][lm] = qq;
      }
    }
  }
  __syncthreads();   // all Ws reads done + sstat written; Ws reusable as Cs

  // ---- C -> LDS f32 [128][128], swz col^(((row>>2)&3)<<4) -> 2-way max ----
  float* Cs = (float*)&Ws[0][0];   // 64KB
#pragma unroll
  for (int m = 0; m < 2; ++m) {
    const int rbase = wid * 32 + m * 16 + lg * 4;
    const int xd = lg << 4;        // == ((rbase>>2)&3)<<4
#pragma unroll
    for (int n = 0; n < 8; ++n) {
      const int col = n * 16 + lm;
#pragma unroll
      for (int j = 0; j < 4; ++j)
        Cs[(rbase + j) * 128 + (col ^ xd)] = acc[m][n][j] + bregs[n];
    }
  }
  __syncthreads();

  // ---- coalesced writeout: 16 thr/row, 16 rows/pass, 8 passes ----
  const int prow = t >> 4;          // 0..15
  const int pcol = (t & 15) * 8;    // 0..120
#pragma unroll
  for (int rb = 0; rb < 8; ++rb) {
    const int row = rb * 16 + prow;
    const int xd = ((row >> 2) & 3) << 4;
    f32x4 v0 = *(const f32x4*)&Cs[row * 128 + (pcol ^ xd)];
    f32x4 v1 = *(const f32x4*)&Cs[row * 128 + ((pcol + 4) ^ xd)];
    if (MODE == 0) {
      const size_t gofs = (size_t)c * NF
                        + (size_t)(bm * 128 + row) * FDIM + bn * 128 + pcol;
      uint4 u;
      u.x = pk2(v0[0], v0[1]); u.y = pk2(v0[2], v0[3]);
      u.z = pk2(v1[0], v1[1]); u.w = pk2(v1[2], v1[3]);
      *(uint4*)(Ybf + gofs) = u;
    } else {
      // residual from xt (bf16 copy of x, (c,n,f) layout): halves FETCH
      const size_t gx = (size_t)c * NF
                      + (size_t)(bm * 128 + row) * FDIM + bn * 128 + pcol;
      uint4 xr = *(const uint4*)(xtres + gx);
      const size_t gofs = (size_t)(bm * 128 + row) * CF + c * FDIM + bn * 128 + pcol;
      float4 o0, o1;
      o0.x = bf_lo(xr.x) + v0[0]; o0.y = bf_hi(xr.x) + v0[1];
      o0.z = bf_lo(xr.y) + v0[2]; o0.w = bf_hi(xr.y) + v0[3];
      o1.x = bf_lo(xr.z) + v1[0]; o1.y = bf_hi(xr.z) + v1[1];
      o1.z = bf_lo(xr.w) + v1[2]; o1.w = bf_hi(xr.w) + v1[3];
      *(float4*)(outf + gofs) = o0;
      *(float4*)(outf + gofs + 4) = o1;
    }
  }

  if (MODE == 0) {
    // ---- partial stats writeout: 256 thr = 2 stats x 128 cols ----
    const int stat = t >> 7;
    const int idx = t & 127;
    const int n = idx >> 4, lmm = idx & 15;
    float v = sstat[stat][0][n][lmm] + sstat[stat][1][n][lmm] +
              sstat[stat][2][n][lmm] + sstat[stat][3][n][lmm];
    float* dst = stat ? pq1 : ps1;
    dst[(size_t)bm * CF + c * FDIM + bn * 128 + n * 16 + lmm] = v;
  }
}

// ---------------- launch ----------------
extern "C" void kernel_launch(void* const* d_in, const int* in_sizes, int n_in,
                              void* d_out, int out_size, void* d_ws, size_t ws_size,
                              hipStream_t stream) {
  const float* x   = (const float*)d_in[0];
  const float* w0  = (const float*)d_in[1];
  const float* b0  = (const float*)d_in[2];
  const float* w1  = (const float*)d_in[3];
  const float* b1  = (const float*)d_in[4];
  const float* g0  = (const float*)d_in[5];
  const float* be0 = (const float*)d_in[6];
  const float* g1  = (const float*)d_in[7];
  const float* be1 = (const float*)d_in[8];
  float* out = (float*)d_out;

  char* ws = (char*)d_ws;
  float* ps0  = (float*)ws;                           // 16*CF
  float* pq0  = ps0 + (size_t)16 * CF;                // 16*CF
  float* ps1  = pq0 + (size_t)16 * CF;                // 16*CF
  float* pq1  = ps1 + (size_t)16 * CF;                // 16*CF
  ushort* w0bf = (ushort*)(pq1 + (size_t)16 * CF);
  ushort* w1bf = w0bf + (size_t)CCH * FDIM * FDIM;
  ushort* xt   = w1bf + (size_t)CCH * FDIM * FDIM;    // (c,n,f) bf16, 67MB
  ushort* ybf  = xt + (size_t)NROWS * CF;             // (c,n,f) bf16, 67MB

  // BN0 stats + x->xt  ||  w0 cvt
  prep<<<1280, 256, 0, stream>>>(x, xt, ps0, pq0, w0, w0bf);

  // linear0: BN0 finalize folded; A=relu(bn0(xt)); out ybf (c,n,f) + BN1 partials
  // + 256 piggyback blocks converting w1 in gemm0's idle bandwidth
  gemm_fused<0, 16><<<2304, 256, 0, stream>>>(
      xt, w0bf, b0, ps0, pq0, g0, be0, nullptr, ybf, nullptr, ps1, pq1,
      w1, w1bf);

  // linear1: BN1 finalize folded; A=relu(bn1(ybf)); out = bf16x(xt) + acc + b1
  gemm_fused<1, 16><<<2048, 256, 0, stream>>>(
      ybf, w1bf, b1, ps1, pq1, g1, be1, xt, nullptr, out, nullptr, nullptr,
      nullptr, nullptr);
}

// Round 18
// 176.861 us; speedup vs baseline: 1.3852x; 1.0097x over previous
//
#include <hip/hip_runtime.h>
#include <hip/hip_bf16.h>

#define NROWS 2048
#define CCH   64
#define FDIM  256
#define CF    16384   // C*F
#define NF    (NROWS * FDIM)
#define EPSV  1e-3f

typedef __attribute__((ext_vector_type(8))) short  short8;
typedef __attribute__((ext_vector_type(4))) float  f32x4;

__device__ __forceinline__ ushort f2bf(float f) {
  union { float f; unsigned u; } v; v.f = f;
  unsigned r = v.u + 0x7fffu + ((v.u >> 16) & 1u);
  return (ushort)(r >> 16);
}
__device__ __forceinline__ float bf_lo(unsigned u) {
  union { unsigned u; float f; } v; v.u = u << 16; return v.f;
}
__device__ __forceinline__ float bf_hi(unsigned u) {
  union { unsigned u; float f; } v; v.u = u & 0xffff0000u; return v.f;
}
__device__ __forceinline__ unsigned pk2(float a, float b) {
  __hip_bfloat162 h = __float22bfloat162_rn(float2{a, b});
  union { __hip_bfloat162 h; unsigned u; } cv; cv.h = h; return cv.u;
}
__device__ __forceinline__ void gll16(const void* g, void* l) {
  __builtin_amdgcn_global_load_lds(
      (const __attribute__((address_space(1))) unsigned*)g,
      (__attribute__((address_space(3))) unsigned*)l, 16, 0, 0);
}

// ---------------- prep: BN0 column stats (no xt)  ||  w0 cvt ----------------
// grid 1280: blocks 0..1023 stats (c = b&63, nb = b>>6); blocks 1024..1279 w0 cvt.
__global__ __launch_bounds__(256) void prep(const float* __restrict__ x,
                                            float* __restrict__ ps,
                                            float* __restrict__ pq,
                                            const float* __restrict__ w0,
                                            ushort* __restrict__ o0) {
  __shared__ float red[2][4][64][4];   // 8KB
  const int b = blockIdx.x;
  const int t = threadIdx.x;
  if (b < 1024) {
    const int c  = b & 63;
    const int nb = b >> 6;
    const int cg = t & 63;             // float4 col group: f = cg*4..cg*4+3
    const int rg = t >> 6;             // 0..3
    const float4* src = (const float4*)x;       // idx = row*4096 + c*64 + cg
    float s0 = 0, s1 = 0, s2 = 0, s3 = 0, q0 = 0, q1 = 0, q2 = 0, q3 = 0;
#pragma unroll 8
    for (int i = 0; i < 32; ++i) {
      const int row = nb * 128 + rg * 32 + i;
      float4 v = src[(size_t)row * 4096 + c * 64 + cg];
      s0 += v.x; q0 += v.x * v.x;
      s1 += v.y; q1 += v.y * v.y;
      s2 += v.z; q2 += v.z * v.z;
      s3 += v.w; q3 += v.w * v.w;
    }
    red[0][rg][cg][0] = s0; red[0][rg][cg][1] = s1;
    red[0][rg][cg][2] = s2; red[0][rg][cg][3] = s3;
    red[1][rg][cg][0] = q0; red[1][rg][cg][1] = q1;
    red[1][rg][cg][2] = q2; red[1][rg][cg][3] = q3;
    __syncthreads();
    if (t < 128) {
      const int which = t >> 6;        // 0=s, 1=q
      const int g = t & 63;
      float* dstp = which ? pq : ps;
#pragma unroll
      for (int j = 0; j < 4; ++j) {
        float v = red[which][0][g][j] + red[which][1][g][j] +
                  red[which][2][g][j] + red[which][3][g][j];
        dstp[(size_t)nb * CF + c * FDIM + g * 4 + j] = v;
      }
    }
  } else {
    const int n4 = CCH * FDIM * FDIM / 4;
    const size_t stride = (size_t)256 * 256;
    for (size_t i = (size_t)(b - 1024) * 256 + t; i < (size_t)n4; i += stride) {
      float4 v = ((const float4*)w0)[i];
      ushort4 u;
      u.x = f2bf(v.x); u.y = f2bf(v.y); u.z = f2bf(v.z); u.w = f2bf(v.w);
      ((ushort4*)o0)[i] = u;
    }
  }
}

// ---------------- fused batched channel GEMM ----------------
// Tile: BM=128 x BN=128 x K=256. GEMM blocks 0..2047 = 16bm x 2bn x 64c. 4 waves,
// each 32 rows x 128 cols (m=2, n=8 frags). W both k-halves staged via gll16
// (XOR-swizzled src+reads) at t=0. A half-batch register pipeline (R10):
// half-0 issued at t=0, half-1 issued before MFMA half-0. BN finalize FOLDED
// into prologue. One vmcnt(0)+barrier, then 128 MFMAs barrier-free.
// MODE 0: A = x f32 (n,cf), BN0+ReLU in-reg; epi ybf (c,n,f) + BN1 partials;
//         blocks 2048..2303 piggyback-convert w1 (rides idle BW).
// MODE 1: A = ybf bf16 (c,n,f), BN1+ReLU in-reg; epi out(n,cf) = x + acc + b.
template <int MODE, int NPARTS>
__global__ __launch_bounds__(256, 2) void gemm_fused(const void* __restrict__ Asrc,
                                                     const ushort* __restrict__ W,
                                                     const float* __restrict__ bias,
                                                     const float* __restrict__ ps,
                                                     const float* __restrict__ pq,
                                                     const float* __restrict__ gam,
                                                     const float* __restrict__ bet,
                                                     const float* __restrict__ xres,
                                                     ushort* __restrict__ Ybf,
                                                     float* __restrict__ outf,
                                                     float* __restrict__ ps1,
                                                     float* __restrict__ pq1,
                                                     const float* __restrict__ wsrc,
                                                     ushort* __restrict__ wdst) {
  __shared__ __align__(16) ushort Ws[2][128 * 128];   // 64KB; reused as Cs f32[128][128]
  __shared__ float scl[256], shf[256];                // 2KB
  __shared__ float sstat[2][4][8][16];                // 4KB (MODE0)

  const int t = threadIdx.x;

  // ---- piggyback blocks (MODE 0 only): convert w1 in gemm0's BW shadow ----
  if (MODE == 0 && blockIdx.x >= 2048) {
    const int n4 = CCH * FDIM * FDIM / 4;
    const size_t stride = (size_t)256 * 256;
    for (size_t i = (size_t)(blockIdx.x - 2048) * 256 + t; i < (size_t)n4; i += stride) {
      float4 v = ((const float4*)wsrc)[i];
      ushort4 u;
      u.x = f2bf(v.x); u.y = f2bf(v.y); u.z = f2bf(v.z); u.w = f2bf(v.w);
      ((ushort4*)wdst)[i] = u;
    }
    return;
  }

  const int lane = t & 63, wid = t >> 6;
  const int lm = lane & 15, lg = lane >> 4;

  // bijective XCD swizzle (gemm blocks 0..2047): XCD j gets wg in [j*256,(j+1)*256)
  const int h  = blockIdx.x;
  const int wg = ((h & 7) << 8) | (h >> 3);
  const int bm = wg & 15, bn = (wg >> 4) & 1, c = wg >> 5;

  // ---- issue ALL W staging now (both halves, 16 gll16/thread) ----
  const int srow = t >> 4;            // 0..15
  const int sb   = (t & 15) * 16;     // 0..240 byte-in-half-row
  const int gsb  = sb ^ ((srow & 7) << 4);
  const char* Wrow = (const char*)(W + ((size_t)c * FDIM + bn * 128) * FDIM);
  char* Ws0 = (char*)&Ws[0][0];
  char* Ws1 = (char*)&Ws[1][0];
#pragma unroll
  for (int i = 0; i < 8; ++i) {
    const int row = i * 16 + srow;
    gll16(Wrow + (size_t)row * 512 + gsb,       Ws0 + row * 256 + sb);
    gll16(Wrow + (size_t)row * 512 + 256 + gsb, Ws1 + row * 256 + sb);
  }

  // ---- A bases ----
  const float*  AbF[2];   // MODE 0: x (n,cf) f32
  const ushort* AbU[2];   // MODE 1: ybf (c,n,f) bf16
#pragma unroll
  for (int m = 0; m < 2; ++m) {
    const int arow = bm * 128 + wid * 32 + m * 16 + lm;
    AbF[m] = (const float*)Asrc + (size_t)arow * CF + c * FDIM + lg * 8;
    AbU[m] = (const ushort*)Asrc + (size_t)c * NF + (size_t)arow * FDIM + lg * 8;
  }

  // ---- A half-batch buffers (explicit, static-indexed) ----
  float4 la[4][2][2];   // MODE0 raw f32 (64 VGPR while live)
  uint4  lu[4][2];      // MODE1 raw bf16x8 (32 VGPR)
  short8 af[4][2];      // converted fragments for current half

#define LOADH(kb)                                                           \
  _Pragma("unroll")                                                         \
  for (int ks = 0; ks < 4; ++ks)                                            \
    _Pragma("unroll")                                                       \
    for (int m = 0; m < 2; ++m) {                                           \
      if (MODE == 0) {                                                      \
        la[ks][m][0] = *(const float4*)(AbF[m] + ((kb) + ks) * 32);         \
        la[ks][m][1] = *(const float4*)(AbF[m] + ((kb) + ks) * 32 + 4);     \
      } else {                                                              \
        lu[ks][m] = *(const uint4*)(AbU[m] + ((kb) + ks) * 32);             \
      }                                                                     \
    }                                                                       \
  __builtin_amdgcn_sched_barrier(0);

  // issue A half-0 with the W burst
  LOADH(0)

  // ---- folded BN finalize: this block's 256 columns (col = c*FDIM + t) ----
  {
    float s = 0, q = 0;
#pragma unroll
    for (int j = 0; j < NPARTS; ++j) {
      s += ps[(size_t)j * CF + c * FDIM + t];
      q += pq[(size_t)j * CF + c * FDIM + t];
    }
    const float mean = s * (1.0f / NROWS);
    const float var  = q * (1.0f / NROWS) - mean * mean;
    const float sc   = gam[c * FDIM + t] * rsqrtf(var + EPSV);
    scl[t] = sc;
    shf[t] = bet[c * FDIM + t] - mean * sc;
  }

  float bregs[8];
#pragma unroll
  for (int n = 0; n < 8; ++n)
    bregs[n] = bias[c * FDIM + bn * 128 + n * 16 + lm];

  f32x4 acc[2][8];
#pragma unroll
  for (int m = 0; m < 2; ++m)
#pragma unroll
    for (int n = 0; n < 8; ++n) acc[m][n] = (f32x4){0.f, 0.f, 0.f, 0.f};

  __syncthreads();   // THE drain: W (both halves) + A half-0 + scl/shf ready

#define CONVH(kb)                                                           \
  _Pragma("unroll")                                                         \
  for (int ks = 0; ks < 4; ++ks) {                                          \
    float4 sc0 = *(const float4*)&scl[((kb) + ks) * 32 + lg * 8];           \
    float4 sc1 = *(const float4*)&scl[((kb) + ks) * 32 + lg * 8 + 4];       \
    float4 sh0 = *(const float4*)&shf[((kb) + ks) * 32 + lg * 8];           \
    float4 sh1 = *(const float4*)&shf[((kb) + ks) * 32 + lg * 8 + 4];       \
    _Pragma("unroll")                                                       \
    for (int m = 0; m < 2; ++m) {                                           \
      float v0, v1, v2, v3, v4, v5, v6, v7;                                 \
      if (MODE == 0) {                                                      \
        float4 a0 = la[ks][m][0];                                           \
        float4 a1 = la[ks][m][1];                                           \
        v0 = a0.x; v1 = a0.y; v2 = a0.z; v3 = a0.w;                         \
        v4 = a1.x; v5 = a1.y; v6 = a1.z; v7 = a1.w;                         \
      } else {                                                              \
        uint4 u = lu[ks][m];                                                \
        v0 = bf_lo(u.x); v1 = bf_hi(u.x); v2 = bf_lo(u.y); v3 = bf_hi(u.y); \
        v4 = bf_lo(u.z); v5 = bf_hi(u.z); v6 = bf_lo(u.w); v7 = bf_hi(u.w); \
      }                                                                     \
      v0 = fmaxf(fmaf(v0, sc0.x, sh0.x), 0.f);                              \
      v1 = fmaxf(fmaf(v1, sc0.y, sh0.y), 0.f);                              \
      v2 = fmaxf(fmaf(v2, sc0.z, sh0.z), 0.f);                              \
      v3 = fmaxf(fmaf(v3, sc0.w, sh0.w), 0.f);                              \
      v4 = fmaxf(fmaf(v4, sc1.x, sh1.x), 0.f);                              \
      v5 = fmaxf(fmaf(v5, sc1.y, sh1.y), 0.f);                              \
      v6 = fmaxf(fmaf(v6, sc1.z, sh1.z), 0.f);                              \
      v7 = fmaxf(fmaf(v7, sc1.w, sh1.w), 0.f);                              \
      union { short8 s; unsigned u[4]; } pkd;                               \
      pkd.u[0] = pk2(v0, v1); pkd.u[1] = pk2(v2, v3);                       \
      pkd.u[2] = pk2(v4, v5); pkd.u[3] = pk2(v6, v7);                       \
      af[ks][m] = pkd.s;                                                    \
    }                                                                       \
  }

#define MFMAH(WsH)                                                          \
  _Pragma("unroll")                                                         \
  for (int ksl = 0; ksl < 4; ++ksl) {                                       \
    short8 bv[8];                                                           \
    _Pragma("unroll")                                                       \
    for (int n = 0; n < 8; ++n) {                                           \
      const int ro = n * 16 + lm;                                           \
      const int byt = (ksl * 64 + lg * 16) ^ ((ro & 7) << 4);               \
      bv[n] = *(const short8*)((WsH) + ro * 256 + byt);                     \
    }                                                                       \
    _Pragma("unroll")                                                       \
    for (int m = 0; m < 2; ++m)                                             \
      _Pragma("unroll")                                                     \
      for (int n = 0; n < 8; ++n)                                           \
        acc[m][n] = __builtin_amdgcn_mfma_f32_16x16x32_bf16(af[ksl][m],     \
                        bv[n], acc[m][n], 0, 0, 0);                         \
  }

  CONVH(0)           // consume half-0 raw (frees la/lu)
  LOADH(4)           // issue half-1 batch before compute
  MFMAH(Ws0)         // 64 MFMAs on half-0
  CONVH(4)           // half-1 (mostly arrived under MFMA)
  MFMAH(Ws1)         // 64 MFMAs on half-1

  if (MODE == 0) {
    // ---- BN1 column partial stats from f32 acc ----
#pragma unroll
    for (int n = 0; n < 8; ++n) {
      float ss = 0, qq = 0;
#pragma unroll
      for (int m = 0; m < 2; ++m)
#pragma unroll
        for (int j = 0; j < 4; ++j) {
          float v = acc[m][n][j] + bregs[n];
          ss += v; qq += v * v;
        }
      ss += __shfl_xor(ss, 16); ss += __shfl_xor(ss, 32);
      qq += __shfl_xor(qq, 16); qq += __shfl_xor(qq, 32);
      if (lg == 0) {
        sstat[0][wid][n][lm] = ss;
        sstat[1][wid][n][lm] = qq;
      }
    }
  }
  __syncthreads();   // all Ws reads done + sstat written; Ws reusable as Cs

  // ---- C -> LDS f32 [128][128], swz col^(((row>>2)&3)<<4) -> 2-way max ----
  float* Cs = (float*)&Ws[0][0];   // 64KB
#pragma unroll
  for (int m = 0; m < 2; ++m) {
    const int rbase = wid * 32 + m * 16 + lg * 4;
    const int xd = lg << 4;        // == ((rbase>>2)&3)<<4
#pragma unroll
    for (int n = 0; n < 8; ++n) {
      const int col = n * 16 + lm;
#pragma unroll
      for (int j = 0; j < 4; ++j)
        Cs[(rbase + j) * 128 + (col ^ xd)] = acc[m][n][j] + bregs[n];
    }
  }
  __syncthreads();

  // ---- coalesced writeout: 16 thr/row, 16 rows/pass, 8 passes ----
  const int prow = t >> 4;          // 0..15
  const int pcol = (t & 15) * 8;    // 0..120
#pragma unroll
  for (int rb = 0; rb < 8; ++rb) {
    const int row = rb * 16 + prow;
    const int xd = ((row >> 2) & 3) << 4;
    f32x4 v0 = *(const f32x4*)&Cs[row * 128 + (pcol ^ xd)];
    f32x4 v1 = *(const f32x4*)&Cs[row * 128 + ((pcol + 4) ^ xd)];
    if (MODE == 0) {
      const size_t gofs = (size_t)c * NF
                        + (size_t)(bm * 128 + row) * FDIM + bn * 128 + pcol;
      uint4 u;
      u.x = pk2(v0[0], v0[1]); u.y = pk2(v0[2], v0[3]);
      u.z = pk2(v1[0], v1[1]); u.w = pk2(v1[2], v1[3]);
      *(uint4*)(Ybf + gofs) = u;
    } else {
      const size_t gofs = (size_t)(bm * 128 + row) * CF + c * FDIM + bn * 128 + pcol;
      float4 x0 = *(const float4*)(xres + gofs);
      float4 x1 = *(const float4*)(xres + gofs + 4);
      float4 o0, o1;
      o0.x = x0.x + v0[0]; o0.y = x0.y + v0[1]; o0.z = x0.z + v0[2]; o0.w = x0.w + v0[3];
      o1.x = x1.x + v1[0]; o1.y = x1.y + v1[1]; o1.z = x1.z + v1[2]; o1.w = x1.w + v1[3];
      *(float4*)(outf + gofs) = o0;
      *(float4*)(outf + gofs + 4) = o1;
    }
  }

  if (MODE == 0) {
    // ---- partial stats writeout: 256 thr = 2 stats x 128 cols ----
    const int stat = t >> 7;
    const int idx = t & 127;
    const int n = idx >> 4, lmm = idx & 15;
    float v = sstat[stat][0][n][lmm] + sstat[stat][1][n][lmm] +
              sstat[stat][2][n][lmm] + sstat[stat][3][n][lmm];
    float* dst = stat ? pq1 : ps1;
    dst[(size_t)bm * CF + c * FDIM + bn * 128 + n * 16 + lmm] = v;
  }
}

// ---------------- launch ----------------
extern "C" void kernel_launch(void* const* d_in, const int* in_sizes, int n_in,
                              void* d_out, int out_size, void* d_ws, size_t ws_size,
                              hipStream_t stream) {
  const float* x   = (const float*)d_in[0];
  const float* w0  = (const float*)d_in[1];
  const float* b0  = (const float*)d_in[2];
  const float* w1  = (const float*)d_in[3];
  const float* b1  = (const float*)d_in[4];
  const float* g0  = (const float*)d_in[5];
  const float* be0 = (const float*)d_in[6];
  const float* g1  = (const float*)d_in[7];
  const float* be1 = (const float*)d_in[8];
  float* out = (float*)d_out;

  char* ws = (char*)d_ws;
  float* ps0  = (float*)ws;                           // 16*CF
  float* pq0  = ps0 + (size_t)16 * CF;                // 16*CF
  float* ps1  = pq0 + (size_t)16 * CF;                // 16*CF
  float* pq1  = ps1 + (size_t)16 * CF;                // 16*CF
  ushort* w0bf = (ushort*)(pq1 + (size_t)16 * CF);
  ushort* w1bf = w0bf + (size_t)CCH * FDIM * FDIM;
  ushort* ybf  = w1bf + (size_t)CCH * FDIM * FDIM;    // (c,n,f) bf16, 67MB

  // BN0 stats || w0 cvt
  prep<<<1280, 256, 0, stream>>>(x, ps0, pq0, w0, w0bf);

  // linear0: BN0 finalize folded; A=relu(bn0(x)) from f32; out ybf (c,n,f)
  // + BN1 partials + 256 piggyback blocks converting w1
  gemm_fused<0, 16><<<2304, 256, 0, stream>>>(
      x, w0bf, b0, ps0, pq0, g0, be0, nullptr, ybf, nullptr, ps1, pq1,
      w1, w1bf);

  // linear1: BN1 finalize folded; A=relu(bn1(ybf)); out = x + acc + b1
  gemm_fused<1, 16><<<2048, 256, 0, stream>>>(
      ybf, w1bf, b1, ps1, pq1, g1, be1, x, nullptr, out, nullptr, nullptr,
      nullptr, nullptr);
}